// Round 7
// baseline (1728.084 us; speedup 1.0000x reference)
//
#include <hip/hip_runtime.h>

typedef unsigned int uint;
typedef unsigned short ushort;

// ---------------------------------------------------------------------------
// GNN scorer, round 7: split dense edge GEMM from sparse aggregation.
//   sort: counting-sort edge indices by dst -> perm/srcp/dstp.
//   proj: ONE linear pass over ef computes G_l = ef @ We_l for all layers,
//         writes bf16 G (strides 64/32/64, line-aligned).
//   per layer: P = h @ Wm[:d] + bm (node GEMM)
//              agg: ng[dst] += relu(P[srcp] + G[perm])   (no LDS/barriers,
//                   run-length-reduced atomics, high-TLP gather kernel)
//              h' = relu([h ; ng] @ Wa + ba)  (apply; L3 fused to rowsum)
//   VM tower folded via w2sum; sigmoid scoring.
// ---------------------------------------------------------------------------

__device__ __forceinline__ ushort f2bf(float f) {
    uint u = __float_as_uint(f);
    u += 0x7FFFu + ((u >> 16) & 1u);          // RNE
    return (ushort)(u >> 16);
}
__device__ __forceinline__ float bf2f(uint s) {
    return __uint_as_float(s << 16);
}

// ---------------- node-side tiled GEMM (MODE 0=store, 1=relu+store, 2=relu+rowsum)
template<int K0, int KP0, int K1, int KP1, int KC, int OUT, int WOUT,
         int NTC, int RPT, int MODE>
__global__ __launch_bounds__(256) void tile_gemm(
    const float* __restrict__ X0, int sx0,
    const float* __restrict__ X1, int sx1,
    const float* __restrict__ Wg, const float* __restrict__ Bg,
    float* __restrict__ Y, int sy, int nR)
{
    constexpr int KPT  = KP0 + KP1;
    constexpr int C4   = KC / 4;
    constexpr int OUTP = 4 * NTC;
    constexpr int NTR  = 256 / NTC;
    constexpr int TR   = NTR * RPT;
    static_assert(TR == 128, "tile must be 128 rows");
    static_assert(KPT % KC == 0, "KC must divide KPT");

    __shared__ float4 Xl[TR * C4];
    __shared__ float4 Wl[KC * NTC];
    __shared__ float  __align__(16) bl[OUTP];

    const int tid = threadIdx.x;
    const int r0  = blockIdx.x * TR;

    for (int idx = tid; idx < OUTP; idx += 256)
        bl[idx] = (Bg != nullptr && idx < OUT) ? Bg[idx] : 0.f;

    const int tc  = tid & (NTC - 1);
    const int tr  = tid / NTC;
    const int key = (RPT * tr) >> 3;

    float4 acc[RPT];
    #pragma unroll
    for (int i = 0; i < RPT; i++) acc[i] = make_float4(0.f, 0.f, 0.f, 0.f);

    for (int kc0 = 0; kc0 < KPT; kc0 += KC) {
        if (kc0 != 0) __syncthreads();
        for (int idx = tid; idx < TR * C4; idx += 256) {
            int r = idx / C4, c = idx - r * C4;
            int col = kc0 + 4 * c;
            int gr = r0 + r;
            float4 v = make_float4(0.f, 0.f, 0.f, 0.f);
            if (gr < nR) {
                if (KP1 == 0 || col < KP0)
                    v = *reinterpret_cast<const float4*>(X0 + (long long)gr * sx0 + col);
                else
                    v = *reinterpret_cast<const float4*>(X1 + (long long)gr * sx1 + (col - KP0));
            }
            int cs = c + ((r >> 3) % C4); if (cs >= C4) cs -= C4;
            Xl[r * C4 + cs] = v;
        }
        for (int idx = tid; idx < KC * OUTP; idx += 256) {
            int kl = idx / OUTP, o = idx - kl * OUTP;
            int k = kc0 + kl;
            float v = 0.f;
            if (o < OUT) {
                if (k < KP0) { if (k < K0) v = Wg[k * OUT + o]; }
                else { int kk = k - KP0; if (kk < K1) v = Wg[(K0 + kk) * OUT + o]; }
            }
            ((float*)Wl)[kl * OUTP + o] = v;
        }
        __syncthreads();

        const int km = key % C4;
        #pragma unroll 4
        for (int k4 = 0; k4 < C4; k4++) {
            int cs = k4 + km; if (cs >= C4) cs -= C4;
            float4 x[RPT];
            #pragma unroll
            for (int i = 0; i < RPT; i++)
                x[i] = Xl[(RPT * tr + i) * C4 + cs];
            #pragma unroll
            for (int kk = 0; kk < 4; kk++) {
                float4 w = Wl[(4 * k4 + kk) * NTC + tc];
                #pragma unroll
                for (int i = 0; i < RPT; i++) {
                    float xs = (kk == 0) ? x[i].x : (kk == 1) ? x[i].y
                             : (kk == 2) ? x[i].z : x[i].w;
                    acc[i].x = fmaf(xs, w.x, acc[i].x);
                    acc[i].y = fmaf(xs, w.y, acc[i].y);
                    acc[i].z = fmaf(xs, w.z, acc[i].z);
                    acc[i].w = fmaf(xs, w.w, acc[i].w);
                }
            }
        }
    }

    const float4 b4 = reinterpret_cast<float4*>(bl)[tc];
    const int o = 4 * tc;

    if (MODE == 0 || MODE == 1) {
        if (o < WOUT) {
            #pragma unroll
            for (int i = 0; i < RPT; i++) {
                int gr = r0 + RPT * tr + i;
                if (gr < nR) {
                    float4 v;
                    v.x = acc[i].x + b4.x; v.y = acc[i].y + b4.y;
                    v.z = acc[i].z + b4.z; v.w = acc[i].w + b4.w;
                    if (MODE == 1) {
                        v.x = fmaxf(v.x, 0.f); v.y = fmaxf(v.y, 0.f);
                        v.z = fmaxf(v.z, 0.f); v.w = fmaxf(v.w, 0.f);
                    }
                    *reinterpret_cast<float4*>(Y + (long long)gr * sy + o) = v;
                }
            }
        }
    } else {
        #pragma unroll
        for (int i = 0; i < RPT; i++) {
            int gr = r0 + RPT * tr + i;
            float s = fmaxf(acc[i].x + b4.x, 0.f) + fmaxf(acc[i].y + b4.y, 0.f)
                    + fmaxf(acc[i].z + b4.z, 0.f) + fmaxf(acc[i].w + b4.w, 0.f);
            #pragma unroll
            for (int off = 1; off < NTC; off <<= 1) s += __shfl_xor(s, off);
            if (tc == 0 && gr < nR) Y[gr] = s;
        }
    }
}

// ---------------- proj: G_l = ef @ We_l (all selected layers, one linear pass)
// 64-row tiles, 256 thr, NTC=16 (OUTP=64), RPT=4, KC=32, K=64 (2 chunks).
template<bool DO1, bool DO2, bool DO3>
__global__ __launch_bounds__(256) void proj_kernel(
    const float* __restrict__ ef,
    const float* __restrict__ We1, const float* __restrict__ We2,
    const float* __restrict__ We3,
    ushort* __restrict__ G1, ushort* __restrict__ G2, ushort* __restrict__ G3,
    int nE)
{
    __shared__ float4 Xl[64 * 8];
    __shared__ float  W1l[32 * 64];
    __shared__ float  W2l[32 * 64];
    __shared__ float  W3l[32 * 64];

    const int tid = threadIdx.x;
    const int r0  = blockIdx.x * 64;
    const int tc  = tid & 15;
    const int tr  = tid >> 4;                 // 0..15, rows 4*tr..4*tr+3
    const int key = ((4 * tr) >> 3) & 7;

    float4 a1[4], a2[4], a3[4];
    #pragma unroll
    for (int i = 0; i < 4; i++) {
        a1[i] = make_float4(0.f, 0.f, 0.f, 0.f);
        a2[i] = make_float4(0.f, 0.f, 0.f, 0.f);
        a3[i] = make_float4(0.f, 0.f, 0.f, 0.f);
    }

    for (int kc0 = 0; kc0 < 64; kc0 += 32) {
        if (kc0 != 0) __syncthreads();
        // stage X (linear ef rows)
        for (int idx = tid; idx < 64 * 8; idx += 256) {
            int r = idx >> 3, c = idx & 7;
            int gr = r0 + r;
            float4 v = make_float4(0.f, 0.f, 0.f, 0.f);
            if (gr < nE)
                v = *reinterpret_cast<const float4*>(ef + (size_t)gr * 64 + kc0 + 4 * c);
            int cs = (c + ((r >> 3) & 7)) & 7;
            Xl[r * 8 + cs] = v;
        }
        // stage W chunks (zero-padded out cols)
        if (DO1)
            for (int idx = tid; idx < 2048; idx += 256) {
                int kl = idx >> 6, o = idx & 63;
                W1l[idx] = (o < 50) ? We1[(kc0 + kl) * 50 + o] : 0.f;
            }
        if (DO2)
            for (int idx = tid; idx < 2048; idx += 256) {
                int kl = idx >> 6, o = idx & 63;
                W2l[idx] = (o < 25) ? We2[(kc0 + kl) * 25 + o] : 0.f;
            }
        if (DO3)
            for (int idx = tid; idx < 2048; idx += 256) {
                int kl = idx >> 6, o = idx & 63;
                W3l[idx] = We3[(kc0 + kl) * 64 + o];
            }
        __syncthreads();

        #pragma unroll 4
        for (int k4 = 0; k4 < 8; k4++) {
            int cs = (k4 + key) & 7;
            float4 xv[4];
            #pragma unroll
            for (int i = 0; i < 4; i++)
                xv[i] = Xl[(4 * tr + i) * 8 + cs];
            #pragma unroll
            for (int kk = 0; kk < 4; kk++) {
                float4 w1, w2, w3;
                if (DO1) w1 = reinterpret_cast<float4*>(W1l)[(4 * k4 + kk) * 16 + tc];
                if (DO2) w2 = reinterpret_cast<float4*>(W2l)[(4 * k4 + kk) * 16 + tc];
                if (DO3) w3 = reinterpret_cast<float4*>(W3l)[(4 * k4 + kk) * 16 + tc];
                #pragma unroll
                for (int i = 0; i < 4; i++) {
                    float xs = (kk == 0) ? xv[i].x : (kk == 1) ? xv[i].y
                             : (kk == 2) ? xv[i].z : xv[i].w;
                    if (DO1) {
                        a1[i].x = fmaf(xs, w1.x, a1[i].x);
                        a1[i].y = fmaf(xs, w1.y, a1[i].y);
                        a1[i].z = fmaf(xs, w1.z, a1[i].z);
                        a1[i].w = fmaf(xs, w1.w, a1[i].w);
                    }
                    if (DO2) {
                        a2[i].x = fmaf(xs, w2.x, a2[i].x);
                        a2[i].y = fmaf(xs, w2.y, a2[i].y);
                        a2[i].z = fmaf(xs, w2.z, a2[i].z);
                        a2[i].w = fmaf(xs, w2.w, a2[i].w);
                    }
                    if (DO3) {
                        a3[i].x = fmaf(xs, w3.x, a3[i].x);
                        a3[i].y = fmaf(xs, w3.y, a3[i].y);
                        a3[i].z = fmaf(xs, w3.z, a3[i].z);
                        a3[i].w = fmaf(xs, w3.w, a3[i].w);
                    }
                }
            }
        }
    }

    #pragma unroll
    for (int i = 0; i < 4; i++) {
        int gr = r0 + 4 * tr + i;
        if (gr >= nE) continue;
        if (DO1) {
            ushort4 u = { f2bf(a1[i].x), f2bf(a1[i].y), f2bf(a1[i].z), f2bf(a1[i].w) };
            *reinterpret_cast<ushort4*>(G1 + (size_t)gr * 64 + 4 * tc) = u;
        }
        if (DO2 && tc < 8) {
            ushort4 u = { f2bf(a2[i].x), f2bf(a2[i].y), f2bf(a2[i].z), f2bf(a2[i].w) };
            *reinterpret_cast<ushort4*>(G2 + (size_t)gr * 32 + 4 * tc) = u;
        }
        if (DO3) {
            ushort4 u = { f2bf(a3[i].x), f2bf(a3[i].y), f2bf(a3[i].z), f2bf(a3[i].w) };
            *reinterpret_cast<ushort4*>(G3 + (size_t)gr * 64 + 4 * tc) = u;
        }
    }
}

// ---------------- agg: ng[dst] += relu(P[srcp] + G[perm]) (run-reduced atomics)
template<int OUT, int GS, int SP, int NCL>
__global__ __launch_bounds__(256) void agg_kernel(
    const ushort* __restrict__ G, const int* __restrict__ perm,
    const int* __restrict__ srcp, const int* __restrict__ dstp,
    const float* __restrict__ P, float* __restrict__ ng, int nE)
{
    constexpr int EPT = 16;
    constexpr int GPB = 256 / NCL;
    const int o   = threadIdx.x & (NCL - 1);
    const int gid = threadIdx.x / NCL;
    const long long base = ((long long)blockIdx.x * GPB + gid) * (long long)EPT;

    float run[8];
    #pragma unroll
    for (int j = 0; j < 8; j++) run[j] = 0.f;
    int rund = -1;

    #pragma unroll 4
    for (int i = 0; i < EPT; i++) {
        long long pos = base + i;
        if (pos >= nE) break;
        int d = dstp[pos];
        int s = srcp[pos];
        int e = perm[pos];
        uint4 gv = *reinterpret_cast<const uint4*>(G + (size_t)e * GS + o * 8);
        const float* pp = P + (size_t)s * SP + o * 8;
        float4 pa = *reinterpret_cast<const float4*>(pp);
        float4 pb = *reinterpret_cast<const float4*>(pp + 4);
        float m[8];
        m[0] = fmaxf(pa.x + bf2f(gv.x & 0xffffu), 0.f);
        m[1] = fmaxf(pa.y + bf2f(gv.x >> 16),     0.f);
        m[2] = fmaxf(pa.z + bf2f(gv.y & 0xffffu), 0.f);
        m[3] = fmaxf(pa.w + bf2f(gv.y >> 16),     0.f);
        m[4] = fmaxf(pb.x + bf2f(gv.z & 0xffffu), 0.f);
        m[5] = fmaxf(pb.y + bf2f(gv.z >> 16),     0.f);
        m[6] = fmaxf(pb.z + bf2f(gv.w & 0xffffu), 0.f);
        m[7] = fmaxf(pb.w + bf2f(gv.w >> 16),     0.f);
        if (d != rund) {
            if (rund >= 0) {
                #pragma unroll
                for (int j = 0; j < 8; j++) {
                    int col = o * 8 + j;
                    if (col < OUT && run[j] != 0.f)
                        atomicAdd(ng + (size_t)rund * 64 + col, run[j]);
                }
            }
            #pragma unroll
            for (int j = 0; j < 8; j++) run[j] = m[j];
            rund = d;
        } else {
            #pragma unroll
            for (int j = 0; j < 8; j++) run[j] += m[j];
        }
    }
    if (rund >= 0) {
        #pragma unroll
        for (int j = 0; j < 8; j++) {
            int col = o * 8 + j;
            if (col < OUT && run[j] != 0.f)
                atomicAdd(ng + (size_t)rund * 64 + col, run[j]);
        }
    }
}

// ---------------- sort-by-dst (counting sort, index-only) ----------------
__global__ __launch_bounds__(256) void hist_kernel(
    const int* __restrict__ dst, int* __restrict__ deg, int nE)
{
    for (int e = blockIdx.x * 256 + threadIdx.x; e < nE; e += gridDim.x * 256)
        atomicAdd(&deg[dst[e]], 1);
}

__global__ __launch_bounds__(1024) void scan_kernel(
    const int* __restrict__ deg, int* __restrict__ rowp, int nN)
{
    __shared__ int wsum[16];
    __shared__ int carry;
    const int tid = threadIdx.x;
    if (tid == 0) carry = 0;
    __syncthreads();
    for (int base = 0; base < nN; base += 1024) {
        int x = (base + tid < nN) ? deg[base + tid] : 0;
        int v = x;
        #pragma unroll
        for (int off = 1; off < 64; off <<= 1) {
            int t = __shfl_up(v, off);
            if ((tid & 63) >= off) v += t;
        }
        if ((tid & 63) == 63) wsum[tid >> 6] = v;
        __syncthreads();
        if (tid < 16) {
            int t = wsum[tid];
            #pragma unroll
            for (int off = 1; off < 16; off <<= 1) {
                int u = __shfl_up(t, off);
                if (tid >= off) t += u;
            }
            wsum[tid] = t;
        }
        __syncthreads();
        int woff = (tid >= 64) ? wsum[(tid >> 6) - 1] : 0;
        int incl = v + woff + carry;
        if (base + tid < nN) rowp[base + tid] = incl - x;
        __syncthreads();
        if (tid == 1023) carry = incl;
        __syncthreads();
    }
    if (tid == 0) rowp[nN] = carry;
}

__global__ __launch_bounds__(256) void scatter_kernel(
    const int* __restrict__ src, const int* __restrict__ dst,
    const int* __restrict__ rowp, int* __restrict__ cursor,
    int* __restrict__ perm, int* __restrict__ srcp, int* __restrict__ dstp, int nE)
{
    for (int e = blockIdx.x * 256 + threadIdx.x; e < nE; e += gridDim.x * 256) {
        int d = dst[e];
        int pos = rowp[d] + atomicAdd(&cursor[d], 1);
        perm[pos] = e;
        srcp[pos] = src[e];
        dstp[pos] = d;
    }
}

// ---------------- VM tower + scoring ----------------
__global__ void w2sum_kernel(const float* __restrict__ W2, const float* __restrict__ b2,
                             float* __restrict__ w2s)
{
    int j = threadIdx.x;  // 128 threads
    float s = 0.f;
    for (int o = 0; o < 64; o++) s += W2[j * 64 + o];
    w2s[j] = s;
    if (j == 0) {
        float bs = 0.f;
        for (int o = 0; o < 64; o++) bs += b2[o];
        w2s[128] = bs;
    }
}

__global__ __launch_bounds__(256) void vm_kernel(
    const float* __restrict__ vmf, const float* __restrict__ W1,
    const float* __restrict__ b1, const float* __restrict__ w2s,
    float* __restrict__ vm_sum, int nV)
{
    const int lane = threadIdx.x & 63;
    const int grp  = threadIdx.x >> 6;
    for (int v = blockIdx.x * 4 + grp; v < nV; v += gridDim.x * 4) {
        const float* vr = vmf + (long long)v * 64;
        float a0 = b1[lane], a1 = b1[lane + 64];
        #pragma unroll 4
        for (int k = 0; k < 64; k += 4) {
            float4 x = *reinterpret_cast<const float4*>(vr + k);
            a0 = fmaf(x.x, W1[(k + 0) * 128 + lane], a0);
            a0 = fmaf(x.y, W1[(k + 1) * 128 + lane], a0);
            a0 = fmaf(x.z, W1[(k + 2) * 128 + lane], a0);
            a0 = fmaf(x.w, W1[(k + 3) * 128 + lane], a0);
            a1 = fmaf(x.x, W1[(k + 0) * 128 + lane + 64], a1);
            a1 = fmaf(x.y, W1[(k + 1) * 128 + lane + 64], a1);
            a1 = fmaf(x.z, W1[(k + 2) * 128 + lane + 64], a1);
            a1 = fmaf(x.w, W1[(k + 3) * 128 + lane + 64], a1);
        }
        float part = fmaxf(a0, 0.f) * w2s[lane] + fmaxf(a1, 0.f) * w2s[lane + 64];
        #pragma unroll
        for (int off = 32; off > 0; off >>= 1) part += __shfl_down(part, off);
        if (lane == 0) vm_sum[v] = part + w2s[128];
    }
}

__global__ __launch_bounds__(256) void score_kernel(
    const int* __restrict__ ec, const int* __restrict__ ev,
    const float* __restrict__ ns, const float* __restrict__ vs,
    float* __restrict__ out, int n)
{
    int i = blockIdx.x * blockDim.x + threadIdx.x;
    if (i < n) {
        float x = ns[ec[i]] + vs[ev[i]];
        out[i] = 1.f / (1.f + expf(-x));
    }
}

extern "C" void kernel_launch(void* const* d_in, const int* in_sizes, int n_in,
                              void* d_out, int out_size, void* d_ws, size_t ws_size,
                              hipStream_t stream)
{
    const float* comp = (const float*)d_in[0];
    const float* ef   = (const float*)d_in[1];
    const float* vmf  = (const float*)d_in[2];
    const int*   src  = (const int*)d_in[3];
    const int*   dst  = (const int*)d_in[4];
    const int*   ecmp = (const int*)d_in[5];
    const int*   evm  = (const int*)d_in[6];
    const float* Wm1 = (const float*)d_in[7];  const float* bm1 = (const float*)d_in[8];
    const float* Wa1 = (const float*)d_in[9];  const float* ba1 = (const float*)d_in[10];
    const float* Wm2 = (const float*)d_in[11]; const float* bm2 = (const float*)d_in[12];
    const float* Wa2 = (const float*)d_in[13]; const float* ba2 = (const float*)d_in[14];
    const float* Wm3 = (const float*)d_in[15]; const float* bm3 = (const float*)d_in[16];
    const float* Wa3 = (const float*)d_in[17]; const float* ba3 = (const float*)d_in[18];
    const float* W1  = (const float*)d_in[19]; const float* b1  = (const float*)d_in[20];
    const float* W2  = (const float*)d_in[21]; const float* b2  = (const float*)d_in[22];

    const int nN = in_sizes[0] / 128;
    const int nE = in_sizes[3];
    const int nV = in_sizes[2] / 64;
    const int nS = in_sizes[5];

    // ---- workspace layout
    float* ws = (float*)d_ws;
    float* bufA     = ws;                        // nN*64: h1(52) / P3(64)
    float* bufB     = bufA + (size_t)nN * 64;    // nN*64: P1(64) / P2(32) / h2(28)
    float* ng       = bufB + (size_t)nN * 64;    // nN*64 neighbor accumulator
    float* node_sum = ng + (size_t)nN * 64;      // nN
    float* vm_sum   = node_sum + nN;             // nV
    float* w2s      = vm_sum + nV;               // 132
    int*   iws      = (int*)(w2s + 132);
    int*   deg      = iws;                       // nN
    int*   rowp     = deg + nN;                  // nN+1
    int*   cursor   = rowp + nN + 1;             // nN
    int*   srcp     = cursor + nN;               // nE
    int*   dstp     = srcp + nE;                 // nE
    int*   perm     = dstp + nE;                 // nE
    // G buffers (bf16) after indices, 256B aligned
    size_t Goff = (((size_t)((char*)(perm + nE) - (char*)d_ws)) + 255) & ~(size_t)255;
    ushort* Gb  = (ushort*)((char*)d_ws + Goff);
    const size_t g1e = (size_t)nE * 64, g2e = (size_t)nE * 32, g3e = (size_t)nE * 64;
    const size_t avail = (ws_size > Goff) ? (ws_size - Goff) / 2 : 0;
    ushort *G1, *G2, *G3; int tier;
    if (avail >= g1e + g2e + g3e) { tier = 0; G1 = Gb; G2 = Gb + g1e; G3 = Gb + g1e + g2e; }
    else if (avail >= g1e + g2e) { tier = 1; G1 = Gb; G2 = Gb + g1e; G3 = Gb; }
    else                         { tier = 2; G1 = Gb; G2 = Gb;       G3 = Gb; }

    float* h1 = bufA;   // stride 52
    float* h2 = bufB;   // stride 28
    float* P1 = bufB;   // stride 64
    float* P2 = bufB;   // stride 32
    float* P3 = bufA;   // stride 64

    const float* We1 = Wm1 + 128 * 50;
    const float* We2 = Wm2 + 50 * 25;
    const float* We3 = Wm3 + 25 * 64;

    const int ngrid  = (nN + 127) / 128;
    const int pgrid  = (nE + 63) / 64;
    const int a1grid = (nE + 511) / 512;     // GPB=32, EPT=16
    const int a2grid = (nE + 1023) / 1024;   // GPB=64
    const int sgrid  = (nE + 255) / 256 < 4096 ? (nE + 255) / 256 : 4096;
    const size_t ngbytes = (size_t)nN * 64 * sizeof(float);

    // ---- one-time counting sort of edge indices by dst
    hipMemsetAsync(deg, 0, (size_t)nN * sizeof(int), stream);
    hist_kernel<<<sgrid, 256, 0, stream>>>(dst, deg, nE);
    scan_kernel<<<1, 1024, 0, stream>>>(deg, rowp, nN);
    hipMemsetAsync(cursor, 0, (size_t)nN * sizeof(int), stream);
    scatter_kernel<<<sgrid, 256, 0, stream>>>(src, dst, rowp, cursor, perm, srcp, dstp, nE);

    // ---- edge projections (linear pass(es) over ef)
    if (tier == 0)
        proj_kernel<true, true, true><<<pgrid, 256, 0, stream>>>(ef, We1, We2, We3, G1, G2, G3, nE);
    else if (tier == 1)
        proj_kernel<true, true, false><<<pgrid, 256, 0, stream>>>(ef, We1, We2, We3, G1, G2, G3, nE);
    else
        proj_kernel<true, false, false><<<pgrid, 256, 0, stream>>>(ef, We1, We2, We3, G1, G2, G3, nE);

    // ================= Layer 1 (D=128 -> 50) =================
    tile_gemm<128,128, 0,0, 64, 50, 64, 16, 8, 0><<<ngrid, 256, 0, stream>>>(
        comp, 128, nullptr, 0, Wm1, bm1, P1, 64, nN);
    hipMemsetAsync(ng, 0, ngbytes, stream);
    agg_kernel<50, 64, 64, 8><<<a1grid, 256, 0, stream>>>(G1, perm, srcp, dstp, P1, ng, nE);
    if (tier == 1)       // G1 dead -> write G3 over it
        proj_kernel<false, false, true><<<pgrid, 256, 0, stream>>>(ef, We1, We2, We3, G1, G2, G3, nE);
    else if (tier == 2)  // G1 dead -> write G2 over it
        proj_kernel<false, true, false><<<pgrid, 256, 0, stream>>>(ef, We1, We2, We3, G1, G2, G3, nE);
    tile_gemm<128,128, 50,52, 60, 50, 52, 16, 8, 1><<<ngrid, 256, 0, stream>>>(
        comp, 128, ng, 64, Wa1, ba1, h1, 52, nN);

    // ================= Layer 2 (50 -> 25) =================
    tile_gemm<50,52, 0,0, 52, 25, 32, 8, 4, 0><<<ngrid, 256, 0, stream>>>(
        h1, 52, nullptr, 0, Wm2, bm2, P2, 32, nN);
    hipMemsetAsync(ng, 0, ngbytes, stream);
    agg_kernel<25, 32, 32, 4><<<a2grid, 256, 0, stream>>>(G2, perm, srcp, dstp, P2, ng, nE);
    if (tier == 2)       // G2 dead -> write G3 over it
        proj_kernel<false, false, true><<<pgrid, 256, 0, stream>>>(ef, We1, We2, We3, G1, G2, G3, nE);
    tile_gemm<50,52, 25,28, 80, 25, 28, 8, 4, 1><<<ngrid, 256, 0, stream>>>(
        h1, 52, ng, 64, Wa2, ba2, h2, 28, nN);

    // ================= Layer 3 (25 -> 64, fused rowsum) =================
    tile_gemm<25,28, 0,0, 28, 64, 64, 16, 8, 0><<<ngrid, 256, 0, stream>>>(
        h2, 28, nullptr, 0, Wm3, bm3, P3, 64, nN);
    hipMemsetAsync(ng, 0, ngbytes, stream);
    agg_kernel<64, 64, 64, 8><<<a1grid, 256, 0, stream>>>(G3, perm, srcp, dstp, P3, ng, nE);
    tile_gemm<25,28, 64,68, 48, 64, 64, 16, 8, 2><<<ngrid, 256, 0, stream>>>(
        h2, 28, ng, 64, Wa3, ba3, node_sum, 1, nN);

    // ================= VM tower (folded) + scores =================
    w2sum_kernel<<<1, 128, 0, stream>>>(W2, b2, w2s);
    vm_kernel<<<(nV + 3) / 4, 256, 0, stream>>>(vmf, W1, b1, w2s, vm_sum, nV);
    score_kernel<<<(nS + 255) / 256, 256, 0, stream>>>(ecmp, evm, node_sum, vm_sum, (float*)d_out, nS);
}

// Round 8
// 914.952 us; speedup vs baseline: 1.8887x; 1.8887x over previous
//
#include <hip/hip_runtime.h>

typedef unsigned int uint;
typedef unsigned short ushort;
typedef short bf16x8 __attribute__((ext_vector_type(8)));
typedef float f32x4  __attribute__((ext_vector_type(4)));

// ---------------------------------------------------------------------------
// GNN scorer, round 8:
//   sort: counting-sort by dst -> srcp (sorted), invperm, rowp (CSR).
//   proj_mfma: bf16 MFMA GEMM  G_l = ef @ We_l, ef read linearly, G written
//              in SORTED order (via invperm) -> agg reads are linear.
//   agg_csr: per-node CSR reduction, no atomics: ng[n] = sum relu(P[s]+G[pos]).
//   node GEMMs (fp32 LDS-tiled) unchanged; VM tower folded; sigmoid scores.
// ---------------------------------------------------------------------------

__device__ __forceinline__ ushort f2bf(float f) {
    uint u = __float_as_uint(f);
    u += 0x7FFFu + ((u >> 16) & 1u);          // RNE
    return (ushort)(u >> 16);
}
__device__ __forceinline__ float bf2f(uint s) {
    return __uint_as_float(s << 16);
}

// ---------------- node-side tiled GEMM (MODE 0=store, 1=relu+store, 2=relu+rowsum)
template<int K0, int KP0, int K1, int KP1, int KC, int OUT, int WOUT,
         int NTC, int RPT, int MODE>
__global__ __launch_bounds__(256) void tile_gemm(
    const float* __restrict__ X0, int sx0,
    const float* __restrict__ X1, int sx1,
    const float* __restrict__ Wg, const float* __restrict__ Bg,
    float* __restrict__ Y, int sy, int nR)
{
    constexpr int KPT  = KP0 + KP1;
    constexpr int C4   = KC / 4;
    constexpr int OUTP = 4 * NTC;
    constexpr int NTR  = 256 / NTC;
    constexpr int TR   = NTR * RPT;
    static_assert(TR == 128, "tile must be 128 rows");
    static_assert(KPT % KC == 0, "KC must divide KPT");

    __shared__ float4 Xl[TR * C4];
    __shared__ float4 Wl[KC * NTC];
    __shared__ float  __align__(16) bl[OUTP];

    const int tid = threadIdx.x;
    const int r0  = blockIdx.x * TR;

    for (int idx = tid; idx < OUTP; idx += 256)
        bl[idx] = (Bg != nullptr && idx < OUT) ? Bg[idx] : 0.f;

    const int tc  = tid & (NTC - 1);
    const int tr  = tid / NTC;
    const int key = (RPT * tr) >> 3;

    float4 acc[RPT];
    #pragma unroll
    for (int i = 0; i < RPT; i++) acc[i] = make_float4(0.f, 0.f, 0.f, 0.f);

    for (int kc0 = 0; kc0 < KPT; kc0 += KC) {
        if (kc0 != 0) __syncthreads();
        for (int idx = tid; idx < TR * C4; idx += 256) {
            int r = idx / C4, c = idx - r * C4;
            int col = kc0 + 4 * c;
            int gr = r0 + r;
            float4 v = make_float4(0.f, 0.f, 0.f, 0.f);
            if (gr < nR) {
                if (KP1 == 0 || col < KP0)
                    v = *reinterpret_cast<const float4*>(X0 + (long long)gr * sx0 + col);
                else
                    v = *reinterpret_cast<const float4*>(X1 + (long long)gr * sx1 + (col - KP0));
            }
            int cs = c + ((r >> 3) % C4); if (cs >= C4) cs -= C4;
            Xl[r * C4 + cs] = v;
        }
        for (int idx = tid; idx < KC * OUTP; idx += 256) {
            int kl = idx / OUTP, o = idx - kl * OUTP;
            int k = kc0 + kl;
            float v = 0.f;
            if (o < OUT) {
                if (k < KP0) { if (k < K0) v = Wg[k * OUT + o]; }
                else { int kk = k - KP0; if (kk < K1) v = Wg[(K0 + kk) * OUT + o]; }
            }
            ((float*)Wl)[kl * OUTP + o] = v;
        }
        __syncthreads();

        const int km = key % C4;
        #pragma unroll 4
        for (int k4 = 0; k4 < C4; k4++) {
            int cs = k4 + km; if (cs >= C4) cs -= C4;
            float4 x[RPT];
            #pragma unroll
            for (int i = 0; i < RPT; i++)
                x[i] = Xl[(RPT * tr + i) * C4 + cs];
            #pragma unroll
            for (int kk = 0; kk < 4; kk++) {
                float4 w = Wl[(4 * k4 + kk) * NTC + tc];
                #pragma unroll
                for (int i = 0; i < RPT; i++) {
                    float xs = (kk == 0) ? x[i].x : (kk == 1) ? x[i].y
                             : (kk == 2) ? x[i].z : x[i].w;
                    acc[i].x = fmaf(xs, w.x, acc[i].x);
                    acc[i].y = fmaf(xs, w.y, acc[i].y);
                    acc[i].z = fmaf(xs, w.z, acc[i].z);
                    acc[i].w = fmaf(xs, w.w, acc[i].w);
                }
            }
        }
    }

    const float4 b4 = reinterpret_cast<float4*>(bl)[tc];
    const int o = 4 * tc;

    if (MODE == 0 || MODE == 1) {
        if (o < WOUT) {
            #pragma unroll
            for (int i = 0; i < RPT; i++) {
                int gr = r0 + RPT * tr + i;
                if (gr < nR) {
                    float4 v;
                    v.x = acc[i].x + b4.x; v.y = acc[i].y + b4.y;
                    v.z = acc[i].z + b4.z; v.w = acc[i].w + b4.w;
                    if (MODE == 1) {
                        v.x = fmaxf(v.x, 0.f); v.y = fmaxf(v.y, 0.f);
                        v.z = fmaxf(v.z, 0.f); v.w = fmaxf(v.w, 0.f);
                    }
                    *reinterpret_cast<float4*>(Y + (long long)gr * sy + o) = v;
                }
            }
        }
    } else {
        #pragma unroll
        for (int i = 0; i < RPT; i++) {
            int gr = r0 + RPT * tr + i;
            float s = fmaxf(acc[i].x + b4.x, 0.f) + fmaxf(acc[i].y + b4.y, 0.f)
                    + fmaxf(acc[i].z + b4.z, 0.f) + fmaxf(acc[i].w + b4.w, 0.f);
            #pragma unroll
            for (int off = 1; off < NTC; off <<= 1) s += __shfl_xor(s, off);
            if (tc == 0 && gr < nR) Y[gr] = s;
        }
    }
}

// ---------------- proj_mfma: G = bf16( ef @ W ), written in sorted order.
// 64-row tiles, 256 thr = 4 waves (wave w owns rows w*16..w*16+15).
// NT col-tiles of 16. SECB: section A = cols 0..63 (stride 64),
// section B = cols 64..95 -> GB (stride 32). !SECB: single section, stride NT*16.
template<int NT, bool SECB>
__global__ __launch_bounds__(256) void proj_mfma(
    const float* __restrict__ ef,
    const float* __restrict__ WA, int wacols,
    const float* __restrict__ WB, int wbcols,
    const int* __restrict__ invperm,
    ushort* __restrict__ GA, ushort* __restrict__ GB, int nE)
{
    constexpr int NCOL = NT * 16;
    constexpr int CLP  = NCOL + 8;        // padded Cl row stride (ushorts)
    constexpr int CPR  = NCOL / 8;        // 16B chunks per output row
    constexpr int GAS  = SECB ? 64 : NCOL; // GA row stride (ushorts)

    __shared__ ushort Al[64 * 64];        // A tile, bf16, XOR-swizzled 16B chunks
    __shared__ ushort Bl[NT * 128 * 8];   // B frags: [(tile*2+ks)*64 + lane]*8
    __shared__ ushort Cl[64 * CLP];
    __shared__ int    sl_pos[64];

    const int tid = threadIdx.x;

    // ---- stage B fragments once per block (fp32 W -> bf16, zero-padded)
    for (int idx = tid; idx < NT * 128; idx += 256) {
        int t  = idx >> 7;
        int ks = (idx >> 6) & 1;
        int l  = idx & 63;
        int col = t * 16 + (l & 15);
        int kb  = ks * 32 + ((l >> 4) << 3);
        ushort u[8];
        #pragma unroll
        for (int j = 0; j < 8; j++) {
            int k = kb + j;
            float w = 0.f;
            if (!SECB || col < 64) { if (col < wacols) w = WA[k * wacols + col]; }
            else { int c2 = col - 64; if (c2 < wbcols) w = WB[k * wbcols + c2]; }
            u[j] = f2bf(w);
        }
        *reinterpret_cast<bf16x8*>(&Bl[idx * 8]) = *reinterpret_cast<bf16x8*>(u);
    }

    const int wv = tid >> 6;
    const int l  = tid & 63;
    const int ntiles = (nE + 63) >> 6;

    for (int tile = blockIdx.x; tile < ntiles; tile += gridDim.x) {
        const int r0 = tile << 6;
        __syncthreads();   // Al/Cl safe to overwrite

        if (tid < 64) sl_pos[tid] = (r0 + tid < nE) ? invperm[r0 + tid] : -1;
        {   // stage A: thread -> (row, 16-wide k chunk); fp32 -> bf16, swizzled
            int row = tid >> 2;
            int kq  = (tid & 3) << 4;
            int gr  = r0 + row;
            float4 f0 = {0,0,0,0}, f1 = {0,0,0,0}, f2 = {0,0,0,0}, f3 = {0,0,0,0};
            if (gr < nE) {
                const float* p = ef + (size_t)gr * 64 + kq;
                f0 = *reinterpret_cast<const float4*>(p);
                f1 = *reinterpret_cast<const float4*>(p + 4);
                f2 = *reinterpret_cast<const float4*>(p + 8);
                f3 = *reinterpret_cast<const float4*>(p + 12);
            }
            ushort u[16];
            u[0]=f2bf(f0.x); u[1]=f2bf(f0.y); u[2]=f2bf(f0.z); u[3]=f2bf(f0.w);
            u[4]=f2bf(f1.x); u[5]=f2bf(f1.y); u[6]=f2bf(f1.z); u[7]=f2bf(f1.w);
            u[8]=f2bf(f2.x); u[9]=f2bf(f2.y); u[10]=f2bf(f2.z); u[11]=f2bf(f2.w);
            u[12]=f2bf(f3.x); u[13]=f2bf(f3.y); u[14]=f2bf(f3.z); u[15]=f2bf(f3.w);
            int kc0 = ((kq >> 3) + 0) ^ (row & 7);
            int kc1 = ((kq >> 3) + 1) ^ (row & 7);
            *reinterpret_cast<bf16x8*>(&Al[(row << 6) + kc0 * 8]) = *reinterpret_cast<bf16x8*>(u);
            *reinterpret_cast<bf16x8*>(&Al[(row << 6) + kc1 * 8]) = *reinterpret_cast<bf16x8*>(u + 8);
        }
        __syncthreads();

        // ---- MFMA: D[m][n] = sum_k A[m][k]*B[k][n]
        f32x4 acc[NT];
        #pragma unroll
        for (int t = 0; t < NT; t++) acc[t] = (f32x4){0.f, 0.f, 0.f, 0.f};
        const int rl = wv * 16 + (l & 15);
        #pragma unroll
        for (int ks = 0; ks < 2; ks++) {
            int kch = (ks * 4 + (l >> 4)) ^ (rl & 7);
            bf16x8 a = *reinterpret_cast<const bf16x8*>(&Al[(rl << 6) + kch * 8]);
            #pragma unroll
            for (int t = 0; t < NT; t++) {
                bf16x8 b = *reinterpret_cast<const bf16x8*>(&Bl[((t * 2 + ks) * 64 + l) * 8]);
                acc[t] = __builtin_amdgcn_mfma_f32_16x16x32_bf16(a, b, acc[t], 0, 0, 0);
            }
        }
        // ---- C -> LDS (bf16); C/D layout: col = l&15, row = (l>>4)*4 + j
        #pragma unroll
        for (int t = 0; t < NT; t++)
            #pragma unroll
            for (int j = 0; j < 4; j++) {
                int rr = wv * 16 + ((l >> 4) << 2) + j;
                Cl[rr * CLP + t * 16 + (l & 15)] = f2bf(acc[t][j]);
            }
        __syncthreads();

        // ---- coalesced sorted-order global write (16B chunks per row)
        for (int idx = tid; idx < 64 * CPR; idx += 256) {
            int row = idx / CPR, c = idx - row * CPR;
            int pos = sl_pos[row];
            if (pos < 0) continue;
            uint4 v = *reinterpret_cast<const uint4*>(&Cl[row * CLP + c * 8]);
            if (!SECB || c < 8)
                *reinterpret_cast<uint4*>(GA + (size_t)pos * GAS + c * 8) = v;
            else
                *reinterpret_cast<uint4*>(GB + (size_t)pos * 32 + (c - 8) * 8) = v;
        }
    }
}

// ---------------- agg_csr: ng[n][:] = sum_{pos in CSR seg} relu(P[srcp[pos]] + G[pos])
template<int NCL, int GS, int SP>
__global__ __launch_bounds__(256) void agg_csr(
    const ushort* __restrict__ G, const int* __restrict__ srcp,
    const int* __restrict__ rowp, const float* __restrict__ P,
    float* __restrict__ ng, int nN)
{
    const int o = threadIdx.x & (NCL - 1);
    const int g = threadIdx.x / NCL;
    const int n = blockIdx.x * (256 / NCL) + g;
    if (n >= nN) return;
    const int s0 = rowp[n], s1 = rowp[n + 1];

    float a0=0,a1=0,a2=0,a3=0,a4=0,a5=0,a6=0,a7=0;
    int pos = s0;
    for (; pos + 2 <= s1; pos += 2) {
        int sA = srcp[pos], sB = srcp[pos + 1];
        uint4 gA = *reinterpret_cast<const uint4*>(G + (size_t)pos * GS + o * 8);
        uint4 gB = *reinterpret_cast<const uint4*>(G + (size_t)(pos + 1) * GS + o * 8);
        const float* pA = P + (size_t)sA * SP + o * 8;
        const float* pB = P + (size_t)sB * SP + o * 8;
        float4 pa0 = *reinterpret_cast<const float4*>(pA);
        float4 pa1 = *reinterpret_cast<const float4*>(pA + 4);
        float4 pb0 = *reinterpret_cast<const float4*>(pB);
        float4 pb1 = *reinterpret_cast<const float4*>(pB + 4);
        a0 += fmaxf(pa0.x + bf2f(gA.x & 0xffffu), 0.f) + fmaxf(pb0.x + bf2f(gB.x & 0xffffu), 0.f);
        a1 += fmaxf(pa0.y + bf2f(gA.x >> 16), 0.f)     + fmaxf(pb0.y + bf2f(gB.x >> 16), 0.f);
        a2 += fmaxf(pa0.z + bf2f(gA.y & 0xffffu), 0.f) + fmaxf(pb0.z + bf2f(gB.y & 0xffffu), 0.f);
        a3 += fmaxf(pa0.w + bf2f(gA.y >> 16), 0.f)     + fmaxf(pb0.w + bf2f(gB.y >> 16), 0.f);
        a4 += fmaxf(pa1.x + bf2f(gA.z & 0xffffu), 0.f) + fmaxf(pb1.x + bf2f(gB.z & 0xffffu), 0.f);
        a5 += fmaxf(pa1.y + bf2f(gA.z >> 16), 0.f)     + fmaxf(pb1.y + bf2f(gB.z >> 16), 0.f);
        a6 += fmaxf(pa1.z + bf2f(gA.w & 0xffffu), 0.f) + fmaxf(pb1.z + bf2f(gB.w & 0xffffu), 0.f);
        a7 += fmaxf(pa1.w + bf2f(gA.w >> 16), 0.f)     + fmaxf(pb1.w + bf2f(gB.w >> 16), 0.f);
    }
    if (pos < s1) {
        int sA = srcp[pos];
        uint4 gA = *reinterpret_cast<const uint4*>(G + (size_t)pos * GS + o * 8);
        const float* pA = P + (size_t)sA * SP + o * 8;
        float4 pa0 = *reinterpret_cast<const float4*>(pA);
        float4 pa1 = *reinterpret_cast<const float4*>(pA + 4);
        a0 += fmaxf(pa0.x + bf2f(gA.x & 0xffffu), 0.f);
        a1 += fmaxf(pa0.y + bf2f(gA.x >> 16), 0.f);
        a2 += fmaxf(pa0.z + bf2f(gA.y & 0xffffu), 0.f);
        a3 += fmaxf(pa0.w + bf2f(gA.y >> 16), 0.f);
        a4 += fmaxf(pa1.x + bf2f(gA.z & 0xffffu), 0.f);
        a5 += fmaxf(pa1.y + bf2f(gA.z >> 16), 0.f);
        a6 += fmaxf(pa1.z + bf2f(gA.w & 0xffffu), 0.f);
        a7 += fmaxf(pa1.w + bf2f(gA.w >> 16), 0.f);
    }
    float4 w0 = {a0, a1, a2, a3}, w1 = {a4, a5, a6, a7};
    float* yp = ng + (size_t)n * 64 + o * 8;
    *reinterpret_cast<float4*>(yp)     = w0;
    *reinterpret_cast<float4*>(yp + 4) = w1;
}

// ---------------- sort-by-dst (counting sort) ----------------
__global__ __launch_bounds__(256) void hist_kernel(
    const int* __restrict__ dst, int* __restrict__ deg, int nE)
{
    for (int e = blockIdx.x * 256 + threadIdx.x; e < nE; e += gridDim.x * 256)
        atomicAdd(&deg[dst[e]], 1);
}

__global__ __launch_bounds__(1024) void scan_kernel(
    const int* __restrict__ deg, int* __restrict__ rowp, int nN)
{
    __shared__ int wsum[16];
    __shared__ int carry;
    const int tid = threadIdx.x;
    if (tid == 0) carry = 0;
    __syncthreads();
    for (int base = 0; base < nN; base += 1024) {
        int x = (base + tid < nN) ? deg[base + tid] : 0;
        int v = x;
        #pragma unroll
        for (int off = 1; off < 64; off <<= 1) {
            int t = __shfl_up(v, off);
            if ((tid & 63) >= off) v += t;
        }
        if ((tid & 63) == 63) wsum[tid >> 6] = v;
        __syncthreads();
        if (tid < 16) {
            int t = wsum[tid];
            #pragma unroll
            for (int off = 1; off < 16; off <<= 1) {
                int u = __shfl_up(t, off);
                if (tid >= off) t += u;
            }
            wsum[tid] = t;
        }
        __syncthreads();
        int woff = (tid >= 64) ? wsum[(tid >> 6) - 1] : 0;
        int incl = v + woff + carry;
        if (base + tid < nN) rowp[base + tid] = incl - x;
        __syncthreads();
        if (tid == 1023) carry = incl;
        __syncthreads();
    }
    if (tid == 0) rowp[nN] = carry;
}

__global__ __launch_bounds__(256) void scatter_kernel(
    const int* __restrict__ src, const int* __restrict__ dst,
    const int* __restrict__ rowp, int* __restrict__ cursor,
    int* __restrict__ srcp, int* __restrict__ invperm, int nE)
{
    for (int e = blockIdx.x * 256 + threadIdx.x; e < nE; e += gridDim.x * 256) {
        int d = dst[e];
        int pos = rowp[d] + atomicAdd(&cursor[d], 1);
        srcp[pos] = src[e];
        invperm[e] = pos;
    }
}

// ---------------- VM tower + scoring ----------------
__global__ void w2sum_kernel(const float* __restrict__ W2, const float* __restrict__ b2,
                             float* __restrict__ w2s)
{
    int j = threadIdx.x;  // 128 threads
    float s = 0.f;
    for (int o = 0; o < 64; o++) s += W2[j * 64 + o];
    w2s[j] = s;
    if (j == 0) {
        float bs = 0.f;
        for (int o = 0; o < 64; o++) bs += b2[o];
        w2s[128] = bs;
    }
}

__global__ __launch_bounds__(256) void vm_kernel(
    const float* __restrict__ vmf, const float* __restrict__ W1,
    const float* __restrict__ b1, const float* __restrict__ w2s,
    float* __restrict__ vm_sum, int nV)
{
    const int lane = threadIdx.x & 63;
    const int grp  = threadIdx.x >> 6;
    for (int v = blockIdx.x * 4 + grp; v < nV; v += gridDim.x * 4) {
        const float* vr = vmf + (long long)v * 64;
        float a0 = b1[lane], a1 = b1[lane + 64];
        #pragma unroll 4
        for (int k = 0; k < 64; k += 4) {
            float4 x = *reinterpret_cast<const float4*>(vr + k);
            a0 = fmaf(x.x, W1[(k + 0) * 128 + lane], a0);
            a0 = fmaf(x.y, W1[(k + 1) * 128 + lane], a0);
            a0 = fmaf(x.z, W1[(k + 2) * 128 + lane], a0);
            a0 = fmaf(x.w, W1[(k + 3) * 128 + lane], a0);
            a1 = fmaf(x.x, W1[(k + 0) * 128 + lane + 64], a1);
            a1 = fmaf(x.y, W1[(k + 1) * 128 + lane + 64], a1);
            a1 = fmaf(x.z, W1[(k + 2) * 128 + lane + 64], a1);
            a1 = fmaf(x.w, W1[(k + 3) * 128 + lane + 64], a1);
        }
        float part = fmaxf(a0, 0.f) * w2s[lane] + fmaxf(a1, 0.f) * w2s[lane + 64];
        #pragma unroll
        for (int off = 32; off > 0; off >>= 1) part += __shfl_down(part, off);
        if (lane == 0) vm_sum[v] = part + w2s[128];
    }
}

__global__ __launch_bounds__(256) void score_kernel(
    const int* __restrict__ ec, const int* __restrict__ ev,
    const float* __restrict__ ns, const float* __restrict__ vs,
    float* __restrict__ out, int n)
{
    int i = blockIdx.x * blockDim.x + threadIdx.x;
    if (i < n) {
        float x = ns[ec[i]] + vs[ev[i]];
        out[i] = 1.f / (1.f + expf(-x));
    }
}

extern "C" void kernel_launch(void* const* d_in, const int* in_sizes, int n_in,
                              void* d_out, int out_size, void* d_ws, size_t ws_size,
                              hipStream_t stream)
{
    const float* comp = (const float*)d_in[0];
    const float* ef   = (const float*)d_in[1];
    const float* vmf  = (const float*)d_in[2];
    const int*   src  = (const int*)d_in[3];
    const int*   dst  = (const int*)d_in[4];
    const int*   ecmp = (const int*)d_in[5];
    const int*   evm  = (const int*)d_in[6];
    const float* Wm1 = (const float*)d_in[7];  const float* bm1 = (const float*)d_in[8];
    const float* Wa1 = (const float*)d_in[9];  const float* ba1 = (const float*)d_in[10];
    const float* Wm2 = (const float*)d_in[11]; const float* bm2 = (const float*)d_in[12];
    const float* Wa2 = (const float*)d_in[13]; const float* ba2 = (const float*)d_in[14];
    const float* Wm3 = (const float*)d_in[15]; const float* bm3 = (const float*)d_in[16];
    const float* Wa3 = (const float*)d_in[17]; const float* ba3 = (const float*)d_in[18];
    const float* W1  = (const float*)d_in[19]; const float* b1  = (const float*)d_in[20];
    const float* W2  = (const float*)d_in[21]; const float* b2  = (const float*)d_in[22];

    const int nN = in_sizes[0] / 128;
    const int nE = in_sizes[3];
    const int nV = in_sizes[2] / 64;
    const int nS = in_sizes[5];

    // ---- workspace layout
    float* ws = (float*)d_ws;
    float* bufA     = ws;                        // nN*64: h1(52) / P3(64)
    float* bufB     = bufA + (size_t)nN * 64;    // nN*64: P1(64) / P2(32) / h2(28)
    float* ng       = bufB + (size_t)nN * 64;    // nN*64 neighbor accumulator
    float* node_sum = ng + (size_t)nN * 64;      // nN
    float* vm_sum   = node_sum + nN;             // nV
    float* w2s      = vm_sum + nV;               // 132
    int*   iws      = (int*)(w2s + 132);
    int*   deg      = iws;                       // nN
    int*   rowp     = deg + nN;                  // nN+1
    int*   cursor   = rowp + nN + 1;             // nN
    int*   srcp     = cursor + nN;               // nE
    int*   invperm  = srcp + nE;                 // nE
    size_t Goff = (((size_t)((char*)(invperm + nE) - (char*)d_ws)) + 255) & ~(size_t)255;
    ushort* G1 = (ushort*)((char*)d_ws + Goff);          // nE*64 ushorts
    ushort* G2 = G1 + (size_t)nE * 64;                   // nE*32 ushorts (two-pass)
    const bool twopass = (Goff + (size_t)nE * 96 * 2) <= ws_size;
    if (!twopass) G2 = G1;   // three-pass: single 205MB buffer reused

    float* h1 = bufA;   // stride 52
    float* h2 = bufB;   // stride 28
    float* P1 = bufB;   // stride 64
    float* P2 = bufB;   // stride 32
    float* P3 = bufA;   // stride 64

    const float* We1 = Wm1 + 128 * 50;
    const float* We2 = Wm2 + 50 * 25;
    const float* We3 = Wm3 + 25 * 64;

    const int ngrid  = (nN + 127) / 128;
    const int ptiles = (nE + 63) / 64;
    const int pgrid  = ptiles < 2048 ? ptiles : 2048;
    const int a8grid = (nN * 8 + 255) / 256;
    const int a4grid = (nN * 4 + 255) / 256;
    const int sgrid  = (nE + 255) / 256 < 4096 ? (nE + 255) / 256 : 4096;

    // ---- one-time counting sort (CSR rowp + sorted srcp + invperm)
    hipMemsetAsync(deg, 0, (size_t)nN * sizeof(int), stream);
    hist_kernel<<<sgrid, 256, 0, stream>>>(dst, deg, nE);
    scan_kernel<<<1, 1024, 0, stream>>>(deg, rowp, nN);
    hipMemsetAsync(cursor, 0, (size_t)nN * sizeof(int), stream);
    scatter_kernel<<<sgrid, 256, 0, stream>>>(src, dst, rowp, cursor, srcp, invperm, nE);

    // ---- projections (bf16 MFMA, sorted output)
    if (twopass)
        proj_mfma<6, true><<<pgrid, 256, 0, stream>>>(ef, We1, 50, We2, 25, invperm, G1, G2, nE);
    else
        proj_mfma<4, false><<<pgrid, 256, 0, stream>>>(ef, We1, 50, nullptr, 0, invperm, G1, nullptr, nE);

    // ================= Layer 1 (D=128 -> 50) =================
    tile_gemm<128,128, 0,0, 64, 50, 64, 16, 8, 0><<<ngrid, 256, 0, stream>>>(
        comp, 128, nullptr, 0, Wm1, bm1, P1, 64, nN);
    agg_csr<8, 64, 64><<<a8grid, 256, 0, stream>>>(G1, srcp, rowp, P1, ng, nN);
    if (!twopass)   // G1 dead -> write G2 (stride 32) into the shared buffer
        proj_mfma<2, false><<<pgrid, 256, 0, stream>>>(ef, We2, 25, nullptr, 0, invperm, G2, nullptr, nE);
    tile_gemm<128,128, 50,52, 60, 50, 52, 16, 8, 1><<<ngrid, 256, 0, stream>>>(
        comp, 128, ng, 64, Wa1, ba1, h1, 52, nN);
    if (twopass)    // G1 dead -> write G3 into G1's buffer
        proj_mfma<4, false><<<pgrid, 256, 0, stream>>>(ef, We3, 64, nullptr, 0, invperm, G1, nullptr, nE);

    // ================= Layer 2 (50 -> 25) =================
    tile_gemm<50,52, 0,0, 52, 25, 32, 8, 4, 0><<<ngrid, 256, 0, stream>>>(
        h1, 52, nullptr, 0, Wm2, bm2, P2, 32, nN);
    agg_csr<4, 32, 32><<<a4grid, 256, 0, stream>>>(G2, srcp, rowp, P2, ng, nN);
    if (!twopass)   // G2 dead -> write G3 into the shared buffer
        proj_mfma<4, false><<<pgrid, 256, 0, stream>>>(ef, We3, 64, nullptr, 0, invperm, G1, nullptr, nE);
    tile_gemm<50,52, 25,28, 80, 25, 28, 8, 4, 1><<<ngrid, 256, 0, stream>>>(
        h1, 52, ng, 64, Wa2, ba2, h2, 28, nN);

    // ================= Layer 3 (25 -> 64, fused rowsum) =================
    tile_gemm<25,28, 0,0, 28, 64, 64, 16, 8, 0><<<ngrid, 256, 0, stream>>>(
        h2, 28, nullptr, 0, Wm3, bm3, P3, 64, nN);
    agg_csr<8, 64, 64><<<a8grid, 256, 0, stream>>>(G1, srcp, rowp, P3, ng, nN);
    tile_gemm<25,28, 64,68, 48, 64, 64, 16, 8, 2><<<ngrid, 256, 0, stream>>>(
        h2, 28, ng, 64, Wa3, ba3, node_sum, 1, nN);

    // ================= VM tower (folded) + scores =================
    w2sum_kernel<<<1, 128, 0, stream>>>(W2, b2, w2s);
    vm_kernel<<<(nV + 3) / 4, 256, 0, stream>>>(vmf, W1, b1, w2s, vm_sum, nV);
    score_kernel<<<(nS + 255) / 256, 256, 0, stream>>>(ecmp, evm, node_sum, vm_sum, (float*)d_out, nS);
}

// Round 9
// 802.599 us; speedup vs baseline: 2.1531x; 1.1400x over previous
//
#include <hip/hip_runtime.h>

typedef unsigned int uint;
typedef unsigned short ushort;
typedef short bf16x8 __attribute__((ext_vector_type(8)));
typedef float f32x4  __attribute__((ext_vector_type(4)));

// ---------------------------------------------------------------------------
// GNN scorer, round 9:
//   sort: counting-sort by dst -> srcp (sorted), invperm, rowp (CSR),
//         multi-block 3-phase scan.
//   proj_all: ONE bf16-MFMA pass over ef computes G1|G2|G3 (sorted order).
//   agg_csr: per-node CSR reduction, no atomics.
//   node GEMMs fp32 LDS-tiled; VM tower folded; sigmoid scores.
// ---------------------------------------------------------------------------

__device__ __forceinline__ ushort f2bf(float f) {
    uint u = __float_as_uint(f);
    u += 0x7FFFu + ((u >> 16) & 1u);          // RNE
    return (ushort)(u >> 16);
}
__device__ __forceinline__ float bf2f(uint s) {
    return __uint_as_float(s << 16);
}

// ---------------- node-side tiled GEMM (MODE 0=store, 1=relu+store, 2=relu+rowsum)
template<int K0, int KP0, int K1, int KP1, int KC, int OUT, int WOUT,
         int NTC, int RPT, int MODE>
__global__ __launch_bounds__(256) void tile_gemm(
    const float* __restrict__ X0, int sx0,
    const float* __restrict__ X1, int sx1,
    const float* __restrict__ Wg, const float* __restrict__ Bg,
    float* __restrict__ Y, int sy, int nR)
{
    constexpr int KPT  = KP0 + KP1;
    constexpr int C4   = KC / 4;
    constexpr int OUTP = 4 * NTC;
    constexpr int NTR  = 256 / NTC;
    constexpr int TR   = NTR * RPT;
    static_assert(TR == 128, "tile must be 128 rows");
    static_assert(KPT % KC == 0, "KC must divide KPT");

    __shared__ float4 Xl[TR * C4];
    __shared__ float4 Wl[KC * NTC];
    __shared__ float  __align__(16) bl[OUTP];

    const int tid = threadIdx.x;
    const int r0  = blockIdx.x * TR;

    for (int idx = tid; idx < OUTP; idx += 256)
        bl[idx] = (Bg != nullptr && idx < OUT) ? Bg[idx] : 0.f;

    const int tc  = tid & (NTC - 1);
    const int tr  = tid / NTC;
    const int key = (RPT * tr) >> 3;

    float4 acc[RPT];
    #pragma unroll
    for (int i = 0; i < RPT; i++) acc[i] = make_float4(0.f, 0.f, 0.f, 0.f);

    for (int kc0 = 0; kc0 < KPT; kc0 += KC) {
        if (kc0 != 0) __syncthreads();
        for (int idx = tid; idx < TR * C4; idx += 256) {
            int r = idx / C4, c = idx - r * C4;
            int col = kc0 + 4 * c;
            int gr = r0 + r;
            float4 v = make_float4(0.f, 0.f, 0.f, 0.f);
            if (gr < nR) {
                if (KP1 == 0 || col < KP0)
                    v = *reinterpret_cast<const float4*>(X0 + (long long)gr * sx0 + col);
                else
                    v = *reinterpret_cast<const float4*>(X1 + (long long)gr * sx1 + (col - KP0));
            }
            int cs = c + ((r >> 3) % C4); if (cs >= C4) cs -= C4;
            Xl[r * C4 + cs] = v;
        }
        for (int idx = tid; idx < KC * OUTP; idx += 256) {
            int kl = idx / OUTP, o = idx - kl * OUTP;
            int k = kc0 + kl;
            float v = 0.f;
            if (o < OUT) {
                if (k < KP0) { if (k < K0) v = Wg[k * OUT + o]; }
                else { int kk = k - KP0; if (kk < K1) v = Wg[(K0 + kk) * OUT + o]; }
            }
            ((float*)Wl)[kl * OUTP + o] = v;
        }
        __syncthreads();

        const int km = key % C4;
        #pragma unroll 4
        for (int k4 = 0; k4 < C4; k4++) {
            int cs = k4 + km; if (cs >= C4) cs -= C4;
            float4 x[RPT];
            #pragma unroll
            for (int i = 0; i < RPT; i++)
                x[i] = Xl[(RPT * tr + i) * C4 + cs];
            #pragma unroll
            for (int kk = 0; kk < 4; kk++) {
                float4 w = Wl[(4 * k4 + kk) * NTC + tc];
                #pragma unroll
                for (int i = 0; i < RPT; i++) {
                    float xs = (kk == 0) ? x[i].x : (kk == 1) ? x[i].y
                             : (kk == 2) ? x[i].z : x[i].w;
                    acc[i].x = fmaf(xs, w.x, acc[i].x);
                    acc[i].y = fmaf(xs, w.y, acc[i].y);
                    acc[i].z = fmaf(xs, w.z, acc[i].z);
                    acc[i].w = fmaf(xs, w.w, acc[i].w);
                }
            }
        }
    }

    const float4 b4 = reinterpret_cast<float4*>(bl)[tc];
    const int o = 4 * tc;

    if (MODE == 0 || MODE == 1) {
        if (o < WOUT) {
            #pragma unroll
            for (int i = 0; i < RPT; i++) {
                int gr = r0 + RPT * tr + i;
                if (gr < nR) {
                    float4 v;
                    v.x = acc[i].x + b4.x; v.y = acc[i].y + b4.y;
                    v.z = acc[i].z + b4.z; v.w = acc[i].w + b4.w;
                    if (MODE == 1) {
                        v.x = fmaxf(v.x, 0.f); v.y = fmaxf(v.y, 0.f);
                        v.z = fmaxf(v.z, 0.f); v.w = fmaxf(v.w, 0.f);
                    }
                    *reinterpret_cast<float4*>(Y + (long long)gr * sy + o) = v;
                }
            }
        }
    } else {
        #pragma unroll
        for (int i = 0; i < RPT; i++) {
            int gr = r0 + RPT * tr + i;
            float s = fmaxf(acc[i].x + b4.x, 0.f) + fmaxf(acc[i].y + b4.y, 0.f)
                    + fmaxf(acc[i].z + b4.z, 0.f) + fmaxf(acc[i].w + b4.w, 0.f);
            #pragma unroll
            for (int off = 1; off < NTC; off <<= 1) s += __shfl_xor(s, off);
            if (tc == 0 && gr < nR) Y[gr] = s;
        }
    }
}

// ---------------- proj_all: single pass, G1|G2|G3 = bf16( ef @ [W1e|W2e|W3e] ),
// written in sorted order. 64-row tiles, 256 thr = 4 waves. 10 col-tiles of 16:
// padded cols 0..63 -> G1 (50 used), 64..95 -> G2 (25 used), 96..159 -> G3 (64).
__global__ __launch_bounds__(256) void proj_all(
    const float* __restrict__ ef,
    const float* __restrict__ W1e, const float* __restrict__ W2e,
    const float* __restrict__ W3e, const int* __restrict__ invperm,
    ushort* __restrict__ G1, ushort* __restrict__ G2, ushort* __restrict__ G3,
    int nE)
{
    constexpr int NT  = 10;
    constexpr int CLP = 168;              // padded Cl row stride (ushorts)

    __shared__ ushort Al[64 * 64];        // A tile, bf16, XOR-swizzled 16B chunks
    __shared__ ushort Bl[NT * 128 * 8];   // B frags
    __shared__ ushort Cl[64 * CLP];
    __shared__ int    sl_pos[64];

    const int tid = threadIdx.x;

    // ---- stage B fragments once per block (fp32 W -> bf16, zero-padded)
    for (int idx = tid; idx < NT * 128; idx += 256) {
        int t  = idx >> 7;
        int ks = (idx >> 6) & 1;
        int l  = idx & 63;
        int gp  = t * 16 + (l & 15);
        int kb  = ks * 32 + ((l >> 4) << 3);
        ushort u[8];
        #pragma unroll
        for (int j = 0; j < 8; j++) {
            int k = kb + j;
            float w = 0.f;
            if (gp < 64)      { if (gp < 50) w = W1e[k * 50 + gp]; }
            else if (gp < 96) { int c = gp - 64; if (c < 25) w = W2e[k * 25 + c]; }
            else              { int c = gp - 96; w = W3e[k * 64 + c]; }
            u[j] = f2bf(w);
        }
        *reinterpret_cast<bf16x8*>(&Bl[idx * 8]) = *reinterpret_cast<bf16x8*>(u);
    }

    const int wv = tid >> 6;
    const int l  = tid & 63;
    const int ntiles = (nE + 63) >> 6;

    for (int tile = blockIdx.x; tile < ntiles; tile += gridDim.x) {
        const int r0 = tile << 6;
        __syncthreads();   // Al/Cl safe to overwrite

        if (tid < 64) sl_pos[tid] = (r0 + tid < nE) ? invperm[r0 + tid] : -1;
        {   // stage A: thread -> (row, 16-wide k chunk); fp32 -> bf16, swizzled
            int row = tid >> 2;
            int kq  = (tid & 3) << 4;
            int gr  = r0 + row;
            float4 f0 = {0,0,0,0}, f1 = {0,0,0,0}, f2 = {0,0,0,0}, f3 = {0,0,0,0};
            if (gr < nE) {
                const float* p = ef + (size_t)gr * 64 + kq;
                f0 = *reinterpret_cast<const float4*>(p);
                f1 = *reinterpret_cast<const float4*>(p + 4);
                f2 = *reinterpret_cast<const float4*>(p + 8);
                f3 = *reinterpret_cast<const float4*>(p + 12);
            }
            ushort u[16];
            u[0]=f2bf(f0.x); u[1]=f2bf(f0.y); u[2]=f2bf(f0.z); u[3]=f2bf(f0.w);
            u[4]=f2bf(f1.x); u[5]=f2bf(f1.y); u[6]=f2bf(f1.z); u[7]=f2bf(f1.w);
            u[8]=f2bf(f2.x); u[9]=f2bf(f2.y); u[10]=f2bf(f2.z); u[11]=f2bf(f2.w);
            u[12]=f2bf(f3.x); u[13]=f2bf(f3.y); u[14]=f2bf(f3.z); u[15]=f2bf(f3.w);
            int kc0 = ((kq >> 3) + 0) ^ (row & 7);
            int kc1 = ((kq >> 3) + 1) ^ (row & 7);
            *reinterpret_cast<bf16x8*>(&Al[(row << 6) + kc0 * 8]) = *reinterpret_cast<bf16x8*>(u);
            *reinterpret_cast<bf16x8*>(&Al[(row << 6) + kc1 * 8]) = *reinterpret_cast<bf16x8*>(u + 8);
        }
        __syncthreads();

        // ---- MFMA
        f32x4 acc[NT];
        #pragma unroll
        for (int t = 0; t < NT; t++) acc[t] = (f32x4){0.f, 0.f, 0.f, 0.f};
        const int rl = wv * 16 + (l & 15);
        #pragma unroll
        for (int ks = 0; ks < 2; ks++) {
            int kch = (ks * 4 + (l >> 4)) ^ (rl & 7);
            bf16x8 a = *reinterpret_cast<const bf16x8*>(&Al[(rl << 6) + kch * 8]);
            #pragma unroll
            for (int t = 0; t < NT; t++) {
                bf16x8 b = *reinterpret_cast<const bf16x8*>(&Bl[((t * 2 + ks) * 64 + l) * 8]);
                acc[t] = __builtin_amdgcn_mfma_f32_16x16x32_bf16(a, b, acc[t], 0, 0, 0);
            }
        }
        // ---- C -> LDS (bf16); C/D layout: col = l&15, row = (l>>4)*4 + j
        #pragma unroll
        for (int t = 0; t < NT; t++)
            #pragma unroll
            for (int j = 0; j < 4; j++) {
                int rr = wv * 16 + ((l >> 4) << 2) + j;
                Cl[rr * CLP + t * 16 + (l & 15)] = f2bf(acc[t][j]);
            }
        __syncthreads();

        // ---- coalesced sorted-order global write (16B chunks per row)
        for (int idx = tid; idx < 64 * 20; idx += 256) {
            int row = idx / 20, c = idx - row * 20;
            int pos = sl_pos[row];
            if (pos < 0) continue;
            uint4 v = *reinterpret_cast<const uint4*>(&Cl[row * CLP + c * 8]);
            if (c < 8)
                *reinterpret_cast<uint4*>(G1 + (size_t)pos * 64 + c * 8) = v;
            else if (c < 12)
                *reinterpret_cast<uint4*>(G2 + (size_t)pos * 32 + (c - 8) * 8) = v;
            else
                *reinterpret_cast<uint4*>(G3 + (size_t)pos * 64 + (c - 12) * 8) = v;
        }
    }
}

// ---------------- proj_mfma (fallback, multi-pass): see round 8.
template<int NT, bool SECB>
__global__ __launch_bounds__(256) void proj_mfma(
    const float* __restrict__ ef,
    const float* __restrict__ WA, int wacols,
    const float* __restrict__ WB, int wbcols,
    const int* __restrict__ invperm,
    ushort* __restrict__ GA, ushort* __restrict__ GB, int nE)
{
    constexpr int NCOL = NT * 16;
    constexpr int CLP  = NCOL + 8;
    constexpr int CPR  = NCOL / 8;
    constexpr int GAS  = SECB ? 64 : NCOL;

    __shared__ ushort Al[64 * 64];
    __shared__ ushort Bl[NT * 128 * 8];
    __shared__ ushort Cl[64 * CLP];
    __shared__ int    sl_pos[64];

    const int tid = threadIdx.x;

    for (int idx = tid; idx < NT * 128; idx += 256) {
        int t  = idx >> 7;
        int ks = (idx >> 6) & 1;
        int l  = idx & 63;
        int col = t * 16 + (l & 15);
        int kb  = ks * 32 + ((l >> 4) << 3);
        ushort u[8];
        #pragma unroll
        for (int j = 0; j < 8; j++) {
            int k = kb + j;
            float w = 0.f;
            if (!SECB || col < 64) { if (col < wacols) w = WA[k * wacols + col]; }
            else { int c2 = col - 64; if (c2 < wbcols) w = WB[k * wbcols + c2]; }
            u[j] = f2bf(w);
        }
        *reinterpret_cast<bf16x8*>(&Bl[idx * 8]) = *reinterpret_cast<bf16x8*>(u);
    }

    const int wv = tid >> 6;
    const int l  = tid & 63;
    const int ntiles = (nE + 63) >> 6;

    for (int tile = blockIdx.x; tile < ntiles; tile += gridDim.x) {
        const int r0 = tile << 6;
        __syncthreads();

        if (tid < 64) sl_pos[tid] = (r0 + tid < nE) ? invperm[r0 + tid] : -1;
        {
            int row = tid >> 2;
            int kq  = (tid & 3) << 4;
            int gr  = r0 + row;
            float4 f0 = {0,0,0,0}, f1 = {0,0,0,0}, f2 = {0,0,0,0}, f3 = {0,0,0,0};
            if (gr < nE) {
                const float* p = ef + (size_t)gr * 64 + kq;
                f0 = *reinterpret_cast<const float4*>(p);
                f1 = *reinterpret_cast<const float4*>(p + 4);
                f2 = *reinterpret_cast<const float4*>(p + 8);
                f3 = *reinterpret_cast<const float4*>(p + 12);
            }
            ushort u[16];
            u[0]=f2bf(f0.x); u[1]=f2bf(f0.y); u[2]=f2bf(f0.z); u[3]=f2bf(f0.w);
            u[4]=f2bf(f1.x); u[5]=f2bf(f1.y); u[6]=f2bf(f1.z); u[7]=f2bf(f1.w);
            u[8]=f2bf(f2.x); u[9]=f2bf(f2.y); u[10]=f2bf(f2.z); u[11]=f2bf(f2.w);
            u[12]=f2bf(f3.x); u[13]=f2bf(f3.y); u[14]=f2bf(f3.z); u[15]=f2bf(f3.w);
            int kc0 = ((kq >> 3) + 0) ^ (row & 7);
            int kc1 = ((kq >> 3) + 1) ^ (row & 7);
            *reinterpret_cast<bf16x8*>(&Al[(row << 6) + kc0 * 8]) = *reinterpret_cast<bf16x8*>(u);
            *reinterpret_cast<bf16x8*>(&Al[(row << 6) + kc1 * 8]) = *reinterpret_cast<bf16x8*>(u + 8);
        }
        __syncthreads();

        f32x4 acc[NT];
        #pragma unroll
        for (int t = 0; t < NT; t++) acc[t] = (f32x4){0.f, 0.f, 0.f, 0.f};
        const int rl = wv * 16 + (l & 15);
        #pragma unroll
        for (int ks = 0; ks < 2; ks++) {
            int kch = (ks * 4 + (l >> 4)) ^ (rl & 7);
            bf16x8 a = *reinterpret_cast<const bf16x8*>(&Al[(rl << 6) + kch * 8]);
            #pragma unroll
            for (int t = 0; t < NT; t++) {
                bf16x8 b = *reinterpret_cast<const bf16x8*>(&Bl[((t * 2 + ks) * 64 + l) * 8]);
                acc[t] = __builtin_amdgcn_mfma_f32_16x16x32_bf16(a, b, acc[t], 0, 0, 0);
            }
        }
        #pragma unroll
        for (int t = 0; t < NT; t++)
            #pragma unroll
            for (int j = 0; j < 4; j++) {
                int rr = wv * 16 + ((l >> 4) << 2) + j;
                Cl[rr * CLP + t * 16 + (l & 15)] = f2bf(acc[t][j]);
            }
        __syncthreads();

        for (int idx = tid; idx < 64 * CPR; idx += 256) {
            int row = idx / CPR, c = idx - row * CPR;
            int pos = sl_pos[row];
            if (pos < 0) continue;
            uint4 v = *reinterpret_cast<const uint4*>(&Cl[row * CLP + c * 8]);
            if (!SECB || c < 8)
                *reinterpret_cast<uint4*>(GA + (size_t)pos * GAS + c * 8) = v;
            else
                *reinterpret_cast<uint4*>(GB + (size_t)pos * 32 + (c - 8) * 8) = v;
        }
    }
}

// ---------------- agg_csr: ng[n][:] = sum_{pos in CSR seg} relu(P[srcp[pos]] + G[pos])
template<int NCL, int GS, int SP>
__global__ __launch_bounds__(256) void agg_csr(
    const ushort* __restrict__ G, const int* __restrict__ srcp,
    const int* __restrict__ rowp, const float* __restrict__ P,
    float* __restrict__ ng, int nN)
{
    const int o = threadIdx.x & (NCL - 1);
    const int g = threadIdx.x / NCL;
    const int n = blockIdx.x * (256 / NCL) + g;
    if (n >= nN) return;
    const int s0 = rowp[n], s1 = rowp[n + 1];

    float a0=0,a1=0,a2=0,a3=0,a4=0,a5=0,a6=0,a7=0;
    int pos = s0;
    for (; pos + 2 <= s1; pos += 2) {
        int sA = srcp[pos], sB = srcp[pos + 1];
        uint4 gA = *reinterpret_cast<const uint4*>(G + (size_t)pos * GS + o * 8);
        uint4 gB = *reinterpret_cast<const uint4*>(G + (size_t)(pos + 1) * GS + o * 8);
        const float* pA = P + (size_t)sA * SP + o * 8;
        const float* pB = P + (size_t)sB * SP + o * 8;
        float4 pa0 = *reinterpret_cast<const float4*>(pA);
        float4 pa1 = *reinterpret_cast<const float4*>(pA + 4);
        float4 pb0 = *reinterpret_cast<const float4*>(pB);
        float4 pb1 = *reinterpret_cast<const float4*>(pB + 4);
        a0 += fmaxf(pa0.x + bf2f(gA.x & 0xffffu), 0.f) + fmaxf(pb0.x + bf2f(gB.x & 0xffffu), 0.f);
        a1 += fmaxf(pa0.y + bf2f(gA.x >> 16), 0.f)     + fmaxf(pb0.y + bf2f(gB.x >> 16), 0.f);
        a2 += fmaxf(pa0.z + bf2f(gA.y & 0xffffu), 0.f) + fmaxf(pb0.z + bf2f(gB.y & 0xffffu), 0.f);
        a3 += fmaxf(pa0.w + bf2f(gA.y >> 16), 0.f)     + fmaxf(pb0.w + bf2f(gB.y >> 16), 0.f);
        a4 += fmaxf(pa1.x + bf2f(gA.z & 0xffffu), 0.f) + fmaxf(pb1.x + bf2f(gB.z & 0xffffu), 0.f);
        a5 += fmaxf(pa1.y + bf2f(gA.z >> 16), 0.f)     + fmaxf(pb1.y + bf2f(gB.z >> 16), 0.f);
        a6 += fmaxf(pa1.z + bf2f(gA.w & 0xffffu), 0.f) + fmaxf(pb1.z + bf2f(gB.w & 0xffffu), 0.f);
        a7 += fmaxf(pa1.w + bf2f(gA.w >> 16), 0.f)     + fmaxf(pb1.w + bf2f(gB.w >> 16), 0.f);
    }
    if (pos < s1) {
        int sA = srcp[pos];
        uint4 gA = *reinterpret_cast<const uint4*>(G + (size_t)pos * GS + o * 8);
        const float* pA = P + (size_t)sA * SP + o * 8;
        float4 pa0 = *reinterpret_cast<const float4*>(pA);
        float4 pa1 = *reinterpret_cast<const float4*>(pA + 4);
        a0 += fmaxf(pa0.x + bf2f(gA.x & 0xffffu), 0.f);
        a1 += fmaxf(pa0.y + bf2f(gA.x >> 16), 0.f);
        a2 += fmaxf(pa0.z + bf2f(gA.y & 0xffffu), 0.f);
        a3 += fmaxf(pa0.w + bf2f(gA.y >> 16), 0.f);
        a4 += fmaxf(pa1.x + bf2f(gA.z & 0xffffu), 0.f);
        a5 += fmaxf(pa1.y + bf2f(gA.z >> 16), 0.f);
        a6 += fmaxf(pa1.z + bf2f(gA.w & 0xffffu), 0.f);
        a7 += fmaxf(pa1.w + bf2f(gA.w >> 16), 0.f);
    }
    float4 w0 = {a0, a1, a2, a3}, w1 = {a4, a5, a6, a7};
    float* yp = ng + (size_t)n * 64 + o * 8;
    *reinterpret_cast<float4*>(yp)     = w0;
    *reinterpret_cast<float4*>(yp + 4) = w1;
}

// ---------------- sort-by-dst (counting sort; 3-phase multi-block scan)
__global__ __launch_bounds__(256) void hist_kernel(
    const int* __restrict__ dst, int* __restrict__ deg, int nE)
{
    for (int e = blockIdx.x * 256 + threadIdx.x; e < nE; e += gridDim.x * 256)
        atomicAdd(&deg[dst[e]], 1);
}

__global__ __launch_bounds__(256) void scan_blksum(
    const int* __restrict__ deg, int* __restrict__ bsum, int nN)
{
    const int t = threadIdx.x;
    const int base = blockIdx.x * 1024;
    int s = 0;
    for (int i = t; i < 1024; i += 256) {
        int id = base + i;
        s += (id < nN) ? deg[id] : 0;
    }
    #pragma unroll
    for (int off = 32; off > 0; off >>= 1) s += __shfl_down(s, off);
    __shared__ int w[4];
    if ((t & 63) == 0) w[t >> 6] = s;
    __syncthreads();
    if (t == 0) bsum[blockIdx.x] = w[0] + w[1] + w[2] + w[3];
}

__global__ __launch_bounds__(256) void scan_top(
    int* __restrict__ bsum, int nB, int* __restrict__ rowp, int nN)
{
    const int t = threadIdx.x;   // nB <= 256
    int v = (t < nB) ? bsum[t] : 0;
    int x = v;
    #pragma unroll
    for (int off = 1; off < 64; off <<= 1) {
        int u = __shfl_up(x, off);
        if ((t & 63) >= off) x += u;
    }
    __shared__ int wsum[4];
    if ((t & 63) == 63) wsum[t >> 6] = x;
    __syncthreads();
    int add = 0;
    #pragma unroll
    for (int i = 0; i < 4; i++) if (i < (t >> 6)) add += wsum[i];
    x += add;
    if (t < nB) bsum[t] = x - v;     // exclusive block offset
    if (t == nB - 1) rowp[nN] = x;   // total
}

__global__ __launch_bounds__(256) void scan_final(
    const int* __restrict__ deg, const int* __restrict__ bsum,
    int* __restrict__ rowp, int nN)
{
    const int t = threadIdx.x;
    const int idx0 = blockIdx.x * 1024 + t * 4;
    int e[4];
    #pragma unroll
    for (int i = 0; i < 4; i++) {
        int id = idx0 + i;
        e[i] = (id < nN) ? deg[id] : 0;
    }
    int tl = e[0] + e[1] + e[2] + e[3];
    int x = tl;
    #pragma unroll
    for (int off = 1; off < 64; off <<= 1) {
        int u = __shfl_up(x, off);
        if ((t & 63) >= off) x += u;
    }
    __shared__ int wsum[4];
    if ((t & 63) == 63) wsum[t >> 6] = x;
    __syncthreads();
    int add = 0;
    #pragma unroll
    for (int i = 0; i < 4; i++) if (i < (t >> 6)) add += wsum[i];
    int run = (x - tl) + add + bsum[blockIdx.x];
    #pragma unroll
    for (int i = 0; i < 4; i++) {
        int id = idx0 + i;
        if (id < nN) rowp[id] = run;
        run += e[i];
    }
}

__global__ __launch_bounds__(256) void scatter_kernel(
    const int* __restrict__ src, const int* __restrict__ dst,
    const int* __restrict__ rowp, int* __restrict__ cursor,
    int* __restrict__ srcp, int* __restrict__ invperm, int nE)
{
    for (int e = blockIdx.x * 256 + threadIdx.x; e < nE; e += gridDim.x * 256) {
        int d = dst[e];
        int pos = rowp[d] + atomicAdd(&cursor[d], 1);
        srcp[pos] = src[e];
        invperm[e] = pos;
    }
}

// ---------------- VM tower + scoring ----------------
__global__ void w2sum_kernel(const float* __restrict__ W2, const float* __restrict__ b2,
                             float* __restrict__ w2s)
{
    int j = threadIdx.x;  // 128 threads
    float s = 0.f;
    for (int o = 0; o < 64; o++) s += W2[j * 64 + o];
    w2s[j] = s;
    if (j == 0) {
        float bs = 0.f;
        for (int o = 0; o < 64; o++) bs += b2[o];
        w2s[128] = bs;
    }
}

__global__ __launch_bounds__(256) void vm_kernel(
    const float* __restrict__ vmf, const float* __restrict__ W1,
    const float* __restrict__ b1, const float* __restrict__ w2s,
    float* __restrict__ vm_sum, int nV)
{
    const int lane = threadIdx.x & 63;
    const int grp  = threadIdx.x >> 6;
    for (int v = blockIdx.x * 4 + grp; v < nV; v += gridDim.x * 4) {
        const float* vr = vmf + (long long)v * 64;
        float a0 = b1[lane], a1 = b1[lane + 64];
        #pragma unroll 4
        for (int k = 0; k < 64; k += 4) {
            float4 x = *reinterpret_cast<const float4*>(vr + k);
            a0 = fmaf(x.x, W1[(k + 0) * 128 + lane], a0);
            a0 = fmaf(x.y, W1[(k + 1) * 128 + lane], a0);
            a0 = fmaf(x.z, W1[(k + 2) * 128 + lane], a0);
            a0 = fmaf(x.w, W1[(k + 3) * 128 + lane], a0);
            a1 = fmaf(x.x, W1[(k + 0) * 128 + lane + 64], a1);
            a1 = fmaf(x.y, W1[(k + 1) * 128 + lane + 64], a1);
            a1 = fmaf(x.z, W1[(k + 2) * 128 + lane + 64], a1);
            a1 = fmaf(x.w, W1[(k + 3) * 128 + lane + 64], a1);
        }
        float part = fmaxf(a0, 0.f) * w2s[lane] + fmaxf(a1, 0.f) * w2s[lane + 64];
        #pragma unroll
        for (int off = 32; off > 0; off >>= 1) part += __shfl_down(part, off);
        if (lane == 0) vm_sum[v] = part + w2s[128];
    }
}

__global__ __launch_bounds__(256) void score_kernel(
    const int* __restrict__ ec, const int* __restrict__ ev,
    const float* __restrict__ ns, const float* __restrict__ vs,
    float* __restrict__ out, int n)
{
    int i = blockIdx.x * blockDim.x + threadIdx.x;
    if (i < n) {
        float x = ns[ec[i]] + vs[ev[i]];
        out[i] = 1.f / (1.f + expf(-x));
    }
}

extern "C" void kernel_launch(void* const* d_in, const int* in_sizes, int n_in,
                              void* d_out, int out_size, void* d_ws, size_t ws_size,
                              hipStream_t stream)
{
    const float* comp = (const float*)d_in[0];
    const float* ef   = (const float*)d_in[1];
    const float* vmf  = (const float*)d_in[2];
    const int*   src  = (const int*)d_in[3];
    const int*   dst  = (const int*)d_in[4];
    const int*   ecmp = (const int*)d_in[5];
    const int*   evm  = (const int*)d_in[6];
    const float* Wm1 = (const float*)d_in[7];  const float* bm1 = (const float*)d_in[8];
    const float* Wa1 = (const float*)d_in[9];  const float* ba1 = (const float*)d_in[10];
    const float* Wm2 = (const float*)d_in[11]; const float* bm2 = (const float*)d_in[12];
    const float* Wa2 = (const float*)d_in[13]; const float* ba2 = (const float*)d_in[14];
    const float* Wm3 = (const float*)d_in[15]; const float* bm3 = (const float*)d_in[16];
    const float* Wa3 = (const float*)d_in[17]; const float* ba3 = (const float*)d_in[18];
    const float* W1  = (const float*)d_in[19]; const float* b1  = (const float*)d_in[20];
    const float* W2  = (const float*)d_in[21]; const float* b2  = (const float*)d_in[22];

    const int nN = in_sizes[0] / 128;
    const int nE = in_sizes[3];
    const int nV = in_sizes[2] / 64;
    const int nS = in_sizes[5];

    // ---- workspace layout
    float* ws = (float*)d_ws;
    float* bufA     = ws;                        // nN*64: h1(52) / P3(64)
    float* bufB     = bufA + (size_t)nN * 64;    // nN*64: P1(64) / P2(32) / h2(28)
    float* ng       = bufB + (size_t)nN * 64;    // nN*64 neighbor accumulator
    float* node_sum = ng + (size_t)nN * 64;      // nN
    float* vm_sum   = node_sum + nN;             // nV
    float* w2s      = vm_sum + nV;               // 132
    int*   iws      = (int*)(w2s + 132);
    int*   deg      = iws;                       // nN   (adjacent to cursor: one memset)
    int*   cursor   = deg + nN;                  // nN
    int*   rowp     = cursor + nN;               // nN+1
    int*   srcp     = rowp + nN + 1;             // nE
    int*   invperm  = srcp + nE;                 // nE
    int*   bsum     = invperm + nE;              // 256
    size_t Goff = (((size_t)((char*)(bsum + 256) - (char*)d_ws)) + 255) & ~(size_t)255;
    ushort* G1 = (ushort*)((char*)d_ws + Goff);          // nE*64 ushorts
    const size_t need_single = (size_t)nE * (64 + 32 + 64) * 2;
    const bool single  = (Goff + need_single) <= ws_size;
    const bool twopass = !single && (Goff + (size_t)nE * 96 * 2) <= ws_size;
    ushort* G2 = single ? (G1 + (size_t)nE * 64)
               : twopass ? (G1 + (size_t)nE * 64) : G1;
    ushort* G3 = single ? (G2 + (size_t)nE * 32) : G1;

    float* h1 = bufA;   // stride 52
    float* h2 = bufB;   // stride 28
    float* P1 = bufB;   // stride 64
    float* P2 = bufB;   // stride 32
    float* P3 = bufA;   // stride 64

    const float* We1 = Wm1 + 128 * 50;
    const float* We2 = Wm2 + 50 * 25;
    const float* We3 = Wm3 + 25 * 64;

    const int ngrid  = (nN + 127) / 128;
    const int ptiles = (nE + 63) / 64;
    const int pgrid  = ptiles < 2048 ? ptiles : 2048;
    const int a8grid = (nN * 8 + 255) / 256;
    const int a4grid = (nN * 4 + 255) / 256;
    const int sgrid  = (nE + 255) / 256 < 4096 ? (nE + 255) / 256 : 4096;
    const int nB     = (nN + 1023) / 1024;   // <= 256 for nN <= 262144

    // ---- one-time counting sort (CSR rowp + sorted srcp + invperm)
    hipMemsetAsync(deg, 0, (size_t)(2 * nN) * sizeof(int), stream);  // deg + cursor
    hist_kernel<<<sgrid, 256, 0, stream>>>(dst, deg, nE);
    scan_blksum<<<nB, 256, 0, stream>>>(deg, bsum, nN);
    scan_top<<<1, 256, 0, stream>>>(bsum, nB, rowp, nN);
    scan_final<<<nB, 256, 0, stream>>>(deg, bsum, rowp, nN);
    scatter_kernel<<<sgrid, 256, 0, stream>>>(src, dst, rowp, cursor, srcp, invperm, nE);

    // ---- projections (bf16 MFMA, sorted output)
    if (single) {
        proj_all<<<pgrid, 256, 0, stream>>>(ef, We1, We2, We3, invperm, G1, G2, G3, nE);
    } else if (twopass) {
        proj_mfma<6, true><<<pgrid, 256, 0, stream>>>(ef, We1, 50, We2, 25, invperm, G1, G2, nE);
    } else {
        proj_mfma<4, false><<<pgrid, 256, 0, stream>>>(ef, We1, 50, nullptr, 0, invperm, G1, nullptr, nE);
    }

    // ================= Layer 1 (D=128 -> 50) =================
    tile_gemm<128,128, 0,0, 64, 50, 64, 16, 8, 0><<<ngrid, 256, 0, stream>>>(
        comp, 128, nullptr, 0, Wm1, bm1, P1, 64, nN);
    agg_csr<8, 64, 64><<<a8grid, 256, 0, stream>>>(G1, srcp, rowp, P1, ng, nN);
    if (!single && !twopass)   // G1 dead -> write G2 (stride 32) into shared buffer
        proj_mfma<2, false><<<pgrid, 256, 0, stream>>>(ef, We2, 25, nullptr, 0, invperm, G2, nullptr, nE);
    tile_gemm<128,128, 50,52, 60, 50, 52, 16, 8, 1><<<ngrid, 256, 0, stream>>>(
        comp, 128, ng, 64, Wa1, ba1, h1, 52, nN);
    if (!single && twopass)    // G1 dead -> write G3 into G1's buffer
        proj_mfma<4, false><<<pgrid, 256, 0, stream>>>(ef, We3, 64, nullptr, 0, invperm, G1, nullptr, nE);

    // ================= Layer 2 (50 -> 25) =================
    tile_gemm<50,52, 0,0, 52, 25, 32, 8, 4, 0><<<ngrid, 256, 0, stream>>>(
        h1, 52, nullptr, 0, Wm2, bm2, P2, 32, nN);
    agg_csr<4, 32, 32><<<a4grid, 256, 0, stream>>>(G2, srcp, rowp, P2, ng, nN);
    if (!single && !twopass)   // G2 dead -> write G3 into shared buffer
        proj_mfma<4, false><<<pgrid, 256, 0, stream>>>(ef, We3, 64, nullptr, 0, invperm, G1, nullptr, nE);
    tile_gemm<50,52, 25,28, 80, 25, 28, 8, 4, 1><<<ngrid, 256, 0, stream>>>(
        h1, 52, ng, 64, Wa2, ba2, h2, 28, nN);

    // ================= Layer 3 (25 -> 64, fused rowsum) =================
    tile_gemm<25,28, 0,0, 28, 64, 64, 16, 8, 0><<<ngrid, 256, 0, stream>>>(
        h2, 28, nullptr, 0, Wm3, bm3, P3, 64, nN);
    agg_csr<8, 64, 64><<<a8grid, 256, 0, stream>>>(G3, srcp, rowp, P3, ng, nN);
    tile_gemm<25,28, 64,68, 48, 64, 64, 16, 8, 2><<<ngrid, 256, 0, stream>>>(
        h2, 28, ng, 64, Wa3, ba3, node_sum, 1, nN);

    // ================= VM tower (folded) + scores =================
    w2sum_kernel<<<1, 128, 0, stream>>>(W2, b2, w2s);
    vm_kernel<<<(nV + 3) / 4, 256, 0, stream>>>(vmf, W1, b1, w2s, vm_sum, nV);
    score_kernel<<<(nS + 255) / 256, 256, 0, stream>>>(ecmp, evm, node_sum, vm_sum, (float*)d_out, nS);
}